// Round 4
// baseline (769.425 us; speedup 1.0000x reference)
//
#include <hip/hip_runtime.h>
#include <math.h>

#define BB  32
#define CC  80
#define TXX 512
#define TYY 2048
#define NEGV -1e9f

// ---------------- prep: o_scale tables, per-t terms, f32 transposed copies ----------------
__global__ __launch_bounds__(256) void k_prep(
    const float* __restrict__ om, const float* __restrict__ ols,
    float* __restrict__ SA, float* __restrict__ SB,
    float* __restrict__ L1, float* __restrict__ L4,
    float* __restrict__ OMTf, float* __restrict__ OLSTf,
    int* __restrict__ DUR)
{
    int gid = blockIdx.x * 256 + threadIdx.x;   // 32*512
    int b = gid >> 9, t = gid & 511;
    const float* pm = om  + (size_t)b * CC * TXX + t;
    const float* pl = ols + (size_t)b * CC * TXX + t;
    float l1 = 0.f, l4 = 0.f;
    for (int c = 0; c < CC; ++c) {
        float m  = pm[(size_t)c * TXX];
        float ls = pl[(size_t)c * TXX];
        float sa = expf(-2.0f * ls);
        l1 += (-0.9189385332046727f - ls);
        l4 += ((-0.5f * m) * m) * sa;
        SA[((size_t)b * CC + c) * TXX + t] = sa;
        SB[((size_t)b * CC + c) * TXX + t] = m * sa;
        OMTf [((size_t)b * TXX + t) * CC + c] = m;
        OLSTf[((size_t)b * TXX + t) * CC + c] = ls;
    }
    L1[gid] = l1; L4[gid] = l4; DUR[gid] = 0;
}

// ---------------- logp GEMM: [Tx,K=80]x[K,Ty] per batch, f32 vector ----------------
__global__ __launch_bounds__(256) void k_logp(
    const float* __restrict__ SA, const float* __restrict__ SB,
    const float* __restrict__ L1, const float* __restrict__ L4,
    const float* __restrict__ z,
    const int* __restrict__ xlp, const int* __restrict__ ylp,
    float* __restrict__ logp)
{
    int b = blockIdx.z;
    int ylen = (ylp[b] >> 1) << 1;
    int s0 = blockIdx.y * 128;
    if (s0 >= ylen) return;            // DP never reads rows >= ylen; k_attn overwrites later
    int t0 = blockIdx.x * 64;
    int xlen = xlp[b];
    int tid = threadIdx.x;

    __shared__ float sA[16][64], sB[16][64], sZ[16][128], sW[16][128];

    float acc2[4][8], acc3[4][8];
    #pragma unroll
    for (int i = 0; i < 4; ++i)
        #pragma unroll
        for (int j = 0; j < 8; ++j) { acc2[i][j] = 0.f; acc3[i][j] = 0.f; }

    int tt = (tid & 15) << 2;   // 4 t per thread
    int ss = (tid >> 4) << 3;   // 8 s per thread
    int r  = tid >> 4;          // staging row 0..15
    int c4 = (tid & 15) << 2;   // staging col (A)
    int s8 = (tid & 15) << 3;   // staging col (Z)

    for (int c0 = 0; c0 < CC; c0 += 16) {
        const float* pa = SA + ((size_t)b * CC + (c0 + r)) * TXX + t0 + c4;
        const float* pb = SB + ((size_t)b * CC + (c0 + r)) * TXX + t0 + c4;
        float4 va = *(const float4*)pa;
        float4 vb = *(const float4*)pb;
        *(float4*)&sA[r][c4] = va;
        *(float4*)&sB[r][c4] = vb;

        const float* pz = z + ((size_t)b * CC + (c0 + r)) * TYY + s0 + s8;
        float4 q0 = *(const float4*)pz;
        float4 q1 = *(const float4*)(pz + 4);
        float zf[8] = {q0.x, q0.y, q0.z, q0.w, q1.x, q1.y, q1.z, q1.w};
        #pragma unroll
        for (int i = 0; i < 8; ++i) {
            sZ[r][s8 + i] = zf[i];
            sW[r][s8 + i] = (-0.5f * zf[i]) * zf[i];
        }
        __syncthreads();
        #pragma unroll
        for (int kc = 0; kc < 16; ++kc) {
            float4 a2 = *(const float4*)&sA[kc][tt];
            float4 a3 = *(const float4*)&sB[kc][tt];
            float4 z0 = *(const float4*)&sZ[kc][ss];
            float4 z1 = *(const float4*)&sZ[kc][ss + 4];
            float4 w0 = *(const float4*)&sW[kc][ss];
            float4 w1 = *(const float4*)&sW[kc][ss + 4];
            float av2[4] = {a2.x, a2.y, a2.z, a2.w};
            float av3[4] = {a3.x, a3.y, a3.z, a3.w};
            float bz[8]  = {z0.x, z0.y, z0.z, z0.w, z1.x, z1.y, z1.z, z1.w};
            float bw[8]  = {w0.x, w0.y, w0.z, w0.w, w1.x, w1.y, w1.z, w1.w};
            #pragma unroll
            for (int i = 0; i < 4; ++i)
                #pragma unroll
                for (int j = 0; j < 8; ++j) {
                    acc2[i][j] = fmaf(av2[i], bw[j], acc2[i][j]);
                    acc3[i][j] = fmaf(av3[i], bz[j], acc3[i][j]);
                }
        }
        __syncthreads();
    }

    float l1a[4], l4a[4]; int bad[4];
    #pragma unroll
    for (int i = 0; i < 4; ++i) {
        int t = t0 + tt + i;
        l1a[i] = L1[b * TXX + t];
        l4a[i] = L4[b * TXX + t];
        bad[i] = (t >= xlen);
    }
    #pragma unroll
    for (int j = 0; j < 8; ++j) {
        int s = s0 + ss + j;
        float vals[4];
        #pragma unroll
        for (int i = 0; i < 4; ++i) {
            float v = ((l1a[i] + acc2[i][j]) + acc3[i][j]) + l4a[i];
            vals[i] = bad[i] ? NEGV : v;
        }
        float4 o; o.x = vals[0]; o.y = vals[1]; o.z = vals[2]; o.w = vals[3];
        *(float4*)&logp[((size_t)b * TYY + s) * TXX + t0 + tt] = o;
    }
}

// ---------------- forward Viterbi DP: 1 wave per batch, emits decision bits ----------------
__device__ __forceinline__ void dp_step(float v[8], float4 c0, float4 c1,
                                        int s_abs, int lane, unsigned char* browBase)
{
    float left = __shfl_up(v[7], 1, 64);
    if (lane == 0) left = NEGV;
    if (s_abs >= 1) {   // bits for row s_abs-1: bit(t) = values[t] < values[t-1]
        unsigned by = 0u;
        by |= (v[0] < left) ? 1u   : 0u;
        by |= (v[1] < v[0]) ? 2u   : 0u;
        by |= (v[2] < v[1]) ? 4u   : 0u;
        by |= (v[3] < v[2]) ? 8u   : 0u;
        by |= (v[4] < v[3]) ? 16u  : 0u;
        by |= (v[5] < v[4]) ? 32u  : 0u;
        by |= (v[6] < v[5]) ? 64u  : 0u;
        by |= (v[7] < v[6]) ? 128u : 0u;
        browBase[(size_t)(s_abs - 1) * 64] = (unsigned char)by;
    }
    float m0 = fmaxf(v[0], left);
    float m1 = fmaxf(v[1], v[0]);
    float m2 = fmaxf(v[2], v[1]);
    float m3 = fmaxf(v[3], v[2]);
    float m4 = fmaxf(v[4], v[3]);
    float m5 = fmaxf(v[5], v[4]);
    float m6 = fmaxf(v[6], v[5]);
    float m7 = fmaxf(v[7], v[6]);
    v[0] = c0.x + m0; v[1] = c0.y + m1; v[2] = c0.z + m2; v[3] = c0.w + m3;
    v[4] = c1.x + m4; v[5] = c1.y + m5; v[6] = c1.z + m6; v[7] = c1.w + m7;
}

__global__ __launch_bounds__(64) void k_fwd(
    const float* __restrict__ logp, const int* __restrict__ ylp,
    unsigned char* __restrict__ BITS)
{
    int b = blockIdx.x, lane = threadIdx.x;
    int n = (ylp[b] >> 1) << 1;     // >= 1024
    const float* lp = logp + (size_t)b * TYY * TXX + lane * 8;
    unsigned char* brow = BITS + (size_t)b * TYY * 64 + lane;
    float v[8];
    #pragma unroll
    for (int k = 0; k < 8; ++k) v[k] = NEGV;
    if (lane == 0) v[0] = 0.0f;

    float4 p0[8], p1[8];
    #pragma unroll
    for (int i = 0; i < 8; ++i) {
        int r = (i < n) ? i : (n - 1);
        p0[i] = *(const float4*)(lp + (size_t)r * TXX);
        p1[i] = *(const float4*)(lp + (size_t)r * TXX + 4);
    }
    int s = 0;
    while (s + 8 <= n) {
        #pragma unroll
        for (int u = 0; u < 8; ++u) {
            float4 c0 = p0[u], c1 = p1[u];
            int pr = s + 8; if (pr > n - 1) pr = n - 1;
            p0[u] = *(const float4*)(lp + (size_t)pr * TXX);
            p1[u] = *(const float4*)(lp + (size_t)pr * TXX + 4);
            dp_step(v, c0, c1, s, lane, brow);
            ++s;
        }
    }
    while (s < n) {
        float4 c0 = *(const float4*)(lp + (size_t)s * TXX);
        float4 c1 = *(const float4*)(lp + (size_t)s * TXX + 4);
        dp_step(v, c0, c1, s, lane, brow);
        ++s;
    }
}

// ---------------- backtrack: chunked 64-bit window walk, 1 wave per batch ----------------
__global__ __launch_bounds__(64) void k_bwd(
    const unsigned char* __restrict__ BITS, const int* __restrict__ xlp,
    const int* __restrict__ ylp, int* __restrict__ TSTAR, int* __restrict__ DUR)
{
    int b = blockIdx.x, lane = threadIdx.x;
    int ylen = (ylp[b] >> 1) << 1;
    int xlen = xlp[b];
    const unsigned char* bb = BITS + (size_t)b * TYY * 64;
    int* tst = TSTAR + b * TYY;
    int idx = xlen - 1;
    int j0 = ylen - 1;
    while (j0 >= 0) {
        int steps = (j0 + 1 < 32) ? (j0 + 1) : 32;
        int row = j0 - 1 - lane;                 // row used at step k==lane
        int bw = idx >> 5; if (bw > 0) --bw;     // 64-bit window covers [idx-32, idx]
        int base_bit = bw << 5;
        unsigned w0 = 0u, w1 = 0u;
        if (lane < steps && row >= 0) {
            const unsigned* rp = (const unsigned*)(bb + (size_t)row * 64);
            w0 = rp[bw]; w1 = rp[bw + 1];        // bw <= 14 since idx <= 511
        }
        unsigned long long wq = (((unsigned long long)w1) << 32) | w0;
        int saved = 0;
        #pragma unroll
        for (int k = 0; k < 32; ++k) {
            if (k >= steps) break;               // uniform
            int j = j0 - k;
            if (lane == k) saved = idx;
            unsigned long long wk = __shfl(wq, k, 64);
            unsigned bit = (unsigned)(wk >> (idx - base_bit)) & 1u;
            int dec = (idx != 0 && j > 0 && (idx == j || bit)) ? 1 : 0;
            idx -= dec;
        }
        if (lane < steps) {
            tst[j0 - lane] = saved;
            atomicAdd(&DUR[b * TXX + saved], 1);
        }
        j0 -= steps;
    }
}

// ---------------- small t-indexed outputs ----------------
__global__ __launch_bounds__(256) void k_small(
    const float* __restrict__ odur, const int* __restrict__ xlp,
    const int* __restrict__ DUR, float* __restrict__ out4,
    float* __restrict__ out5)
{
    int gid = blockIdx.x * 256 + threadIdx.x;
    int b = gid >> 9, t = gid & 511;
    out4[gid] = odur[gid];
    int xlen = xlp[b];
    float d = (float)DUR[gid];
    out5[gid] = (t < xlen) ? log1pf(d) : 0.0f;
}

// ---------------- z transpose + gathers (out0, out1, out2) ----------------
__global__ __launch_bounds__(256) void k_out_sc(
    const float* __restrict__ z, const float* __restrict__ OMTf,
    const float* __restrict__ OLSTf, const int* __restrict__ TSTAR,
    const int* __restrict__ ylp,
    float* __restrict__ out0, float* __restrict__ out1,
    float* __restrict__ out2)
{
    int b = blockIdx.y;
    int s0 = blockIdx.x * 32;
    int tid = threadIdx.x;
    int ylen = (ylp[b] >> 1) << 1;
    __shared__ int sT[32];
    __shared__ float zt[32][81];
    if (tid < 32) {
        int s = s0 + tid;
        sT[tid] = (s < ylen) ? TSTAR[b * TYY + s] : 0;
    }
    int c_l = tid >> 5, s_l = tid & 31;
    #pragma unroll
    for (int cp = 0; cp < 10; ++cp) {
        int c = cp * 8 + c_l;
        zt[s_l][c] = z[((size_t)b * CC + c) * TYY + s0 + s_l];
    }
    __syncthreads();
    for (int e = tid; e < 32 * 80; e += 256) {
        int sl = e / 80;
        int cc = e - sl * 80;
        int s = s0 + sl;
        bool valid = s < ylen;
        int t = sT[sl];
        size_t o = ((size_t)b * TYY + s) * 80 + cc;
        size_t g = ((size_t)b * TXX + t) * 80 + cc;
        out0[o] = valid ? zt[sl][cc] : 0.0f;
        out1[o] = valid ? OMTf[g]    : 0.0f;
        out2[o] = valid ? OLSTf[g]   : 0.0f;
    }
}

// ---------------- alignments (out3), one-hot rows ----------------
__global__ __launch_bounds__(256) void k_attn(
    const int* __restrict__ TSTAR, const int* __restrict__ ylp,
    float* __restrict__ out3)
{
    int b = blockIdx.y;
    int s0 = blockIdx.x * 16;
    int tid = threadIdx.x;
    int ylen = (ylp[b] >> 1) << 1;
    #pragma unroll
    for (int r = 0; r < 16; ++r) {
        int s = s0 + r;
        int tr = (s < ylen) ? TSTAR[b * TYY + s] : -1;
        int t = tid << 1;
        float2 val;
        val.x = (t == tr) ? 1.0f : 0.0f;
        val.y = (t + 1 == tr) ? 1.0f : 0.0f;
        ((float2*)(out3 + ((size_t)b * TYY + s) * TXX))[tid] = val;
    }
}

extern "C" void kernel_launch(void* const* d_in, const int* in_sizes, int n_in,
                              void* d_out, int out_size, void* d_ws, size_t ws_size,
                              hipStream_t stream)
{
    const float* om   = (const float*)d_in[0];
    const float* ols  = (const float*)d_in[1];
    const float* odur = (const float*)d_in[2];
    const float* z    = (const float*)d_in[3];
    const int* xl = (const int*)d_in[4];
    const int* yl = (const int*)d_in[5];

    float* out0 = (float*)d_out;            // [B,Ty,C]  5,242,880 f32
    float* out1 = out0 + 5242880;           // [B,Ty,C]
    float* out2 = out0 + 10485760;          // [B,Ty,C]
    float* out3 = out0 + 15728640;          // [B,Ty,Tx] 33,554,432 f32
    float* out4 = out0 + 49283072;          // [B,Tx,1]
    float* out5 = out0 + 49299456;          // [B,Tx,1]

    // Scratch aliased into d_out (stream-ordered: consumers finish before overwrite):
    float* SA   = out0;                     // 1,310,720 f32 (out0 region; k_out_sc writes out0 after k_logp)
    float* SB   = out0 + 1310720;           // 1,310,720 f32
    float* logp = out3;                     // 33,554,432 f32 == exactly out3's region; k_attn overwrites last

    // Workspace (15,138,816 B total)
    char* ws = (char*)d_ws;
    float* L1 = (float*)ws;                                  // 65,536 B
    float* L4 = (float*)(ws + 65536);                        // 65,536 B
    float* OMTf  = (float*)(ws + 131072);                    // 5,242,880 B
    float* OLSTf = (float*)(ws + 5373952);                   // 5,242,880 B
    unsigned char* BITS = (unsigned char*)(ws + 10616832);   // 4,194,304 B
    int* TSTAR = (int*)(ws + 14811136);                      // 262,144 B
    int* DUR   = (int*)(ws + 15073280);                      // 65,536 B

    hipLaunchKernelGGL(k_prep, dim3(64), dim3(256), 0, stream,
                       om, ols, SA, SB, L1, L4, OMTf, OLSTf, DUR);
    hipLaunchKernelGGL(k_logp, dim3(8, 16, 32), dim3(256), 0, stream,
                       SA, SB, L1, L4, z, xl, yl, logp);
    hipLaunchKernelGGL(k_fwd, dim3(32), dim3(64), 0, stream, logp, yl, BITS);
    hipLaunchKernelGGL(k_bwd, dim3(32), dim3(64), 0, stream, BITS, xl, yl, TSTAR, DUR);
    hipLaunchKernelGGL(k_small, dim3(64), dim3(256), 0, stream, odur, xl, DUR, out4, out5);
    hipLaunchKernelGGL(k_out_sc, dim3(64, 32), dim3(256), 0, stream,
                       z, OMTf, OLSTf, TSTAR, yl, out0, out1, out2);
    hipLaunchKernelGGL(k_attn, dim3(128, 32), dim3(256), 0, stream, TSTAR, yl, out3);
}